// Round 13
// baseline (3041.099 us; speedup 1.0000x reference)
//
#include <hip/hip_runtime.h>
#include <hip/hip_bf16.h>

// Cos_RootHist_GLM — f32 in/out (passing since round 10, absmax 0.125).
// R13: scan pair-parallel steps (hist[0]==0 -> y_t independent of y_{t-1}),
// interleaved [u][4] coeff table (1 ds_read_b128/step), static role->row
// mapping (rotation cancels), 4-body sub-chunk macro.

#define DEVINL __device__ __forceinline__

static constexpr int T_DATA = 20000;
static constexpr int N_E = 2000;
static constexpr int N_I = 500;
static constexpr int SUB = 15;
static constexpr int T_NO = 200;
static constexpr int NB = 19;

// ws layout (f32 offsets) — total 670720 f32 = 2.683 MB
static constexpr int EKT_OFF = 0;       // [200][16] e-kern transposed
static constexpr int IKT_OFF = 3200;    // [200][16]
static constexpr int HT_OFF  = 6400;    // 256
static constexpr int PRM_OFF = 6656;    // 0..14 wsub2, 16..30 theta, 33 scale, 34 vo
static constexpr int WE_OFF  = 6720;    // 2000
static constexpr int WI_OFF  = 8720;    // 500
static constexpr int IDXE_B  = 36880;   // byte off, 2000 uchar
static constexpr int IDXI_B  = 38880;   // byte off, 500 uchar
static constexpr int BT_OFF  = 9856;    // 20736 (zero-padded past 20000)
static constexpr int SYNE_OFF = 30720;  // [20000][16]
static constexpr int SYNI_OFF = 350720; // [20000][16]
static constexpr int WS_END  = 670720;

DEVINL float fast_exp2(float x) {
#if __has_builtin(__builtin_amdgcn_exp2f)
  return __builtin_amdgcn_exp2f(x);
#else
  return exp2f(x);
#endif
}
DEVINL float fast_log2(float x) {
#if __has_builtin(__builtin_amdgcn_logf)
  return __builtin_amdgcn_logf(x);
#else
  return log2f(x);
#endif
}
DEVINL float rlane(float v, int l) {
  return __builtin_bit_cast(float, __builtin_amdgcn_readlane(__builtin_bit_cast(int, v), l));
}

DEVINL float softplus_f(float x) {
  float z = x * 1.44269504088896f;
  float l = 0.6931471805599453f * fast_log2(1.0f + fast_exp2(z));
  return (x > 16.0f) ? x : l;
}

// ---------------- prep ----------------
__global__ __launch_bounds__(256) void prep_kernel(
    const float* __restrict__ Cse, const float* __restrict__ Csi,
    const float* __restrict__ cosb, const float* __restrict__ Wsyn,
    const float* __restrict__ Wsub, const float* __restrict__ Vo,
    const float* __restrict__ Theta, const float* __restrict__ Whist,
    float* __restrict__ ws, float* __restrict__ outF) {
  const int tid = threadIdx.x;
  float* ekT = ws + EKT_OFF;
  float* ikT = ws + IKT_OFF;
  float* ht  = ws + HT_OFF;
  float* prm = ws + PRM_OFF;
  float* we  = ws + WE_OFF;
  float* wi  = ws + WI_OFF;
  unsigned char* idxe = (unsigned char*)ws + IDXE_B;
  unsigned char* idxi = (unsigned char*)ws + IDXI_B;
  float* bT  = ws + BT_OFF;

  for (int p = tid; p < SUB * T_NO; p += 256) {
    int s = p / T_NO, j = p - s * T_NO;
    float ae = 0.f, ai = 0.f;
    for (int b = 0; b < NB; ++b) {
      float cb = cosb[b * T_NO + j];
      ae = fmaf(Wsyn[(s * NB + b) * 2 + 0], cb, ae);
      ai = fmaf(Wsyn[(s * NB + b) * 2 + 1], cb, ai);
    }
    ekT[j * 16 + s] = ae;
    ikT[j * 16 + s] = ai;
    outF[p] = ae;
    outF[SUB * T_NO + p] = ai;
  }
  for (int j = tid; j < T_NO; j += 256) { ekT[j * 16 + 15] = 0.f; ikT[j * 16 + 15] = 0.f; }
  if (tid < 256) {
    float hv = 0.f;
    if (tid < T_NO) {
      for (int b = 0; b < NB; ++b) hv = fmaf(Whist[b], cosb[b * T_NO + tid], hv);
      outF[30 * T_NO + tid] = hv;
    }
    ht[tid] = (tid < T_NO) ? hv : 0.f;   // ht[0] == hist[0] == 0 exactly
  }
  for (int n = tid; n < N_E; n += 256) {
    int id = 0; float w = 0.f;
    for (int s = 0; s < SUB; ++s) { float c = Cse[s * N_E + n]; if (c != 0.f) { id = s; w = c; } }
    idxe[n] = (unsigned char)id; we[n] = w;
  }
  for (int n = tid; n < N_I; n += 256) {
    int id = 0; float w = 0.f;
    for (int s = 0; s < SUB; ++s) { float c = Csi[s * N_I + n]; if (c != 0.f) { id = s; w = c; } }
    idxi[n] = (unsigned char)id; wi[n] = w;
  }
  if (tid < SUB) {
    float w = Wsub[tid];
    prm[tid] = w * w;
    prm[16 + tid] = Theta[tid];
  }
  if (tid == 0) {
    float w0 = Wsub[0];
    prm[33] = w0 * w0;
    prm[34] = Vo[0];
  }
  for (int p = T_DATA + tid; p < T_DATA + 736; p += 256) bT[p] = 0.f;
}

// ---------------- pool: wave per t-row, float4 loads, LDS atomics ----------------
__global__ __launch_bounds__(256) void pool_kernel(
    const float* __restrict__ Se, const float* __restrict__ Si,
    float* __restrict__ ws) {
  __shared__ float cnt[4][32];   // [wave][0:16 E | 16:32 I]
  const int lane = threadIdx.x & 63;
  const int w = threadIdx.x >> 6;
  const int t = blockIdx.x * 4 + w;
  if (lane < 32) cnt[w][lane] = 0.f;
  __syncthreads();
  const float* we = ws + WE_OFF;
  const float* wi = ws + WI_OFF;
  const unsigned int* ie = (const unsigned int*)((const char*)ws + IDXE_B);
  const unsigned int* ii = (const unsigned int*)((const char*)ws + IDXI_B);

  const float4* rowE = (const float4*)(Se + (size_t)t * N_E);   // 500 float4
#pragma unroll
  for (int k = 0; k < 8; ++k) {
    int c = k * 64 + lane;
    if (c < 500) {
      float4 v = rowE[c];
      unsigned int b = ie[c];
      if (v.x != 0.f) atomicAdd(&cnt[w][(b      ) & 0xFFu], v.x * we[c * 4 + 0]);
      if (v.y != 0.f) atomicAdd(&cnt[w][(b >>  8) & 0xFFu], v.y * we[c * 4 + 1]);
      if (v.z != 0.f) atomicAdd(&cnt[w][(b >> 16) & 0xFFu], v.z * we[c * 4 + 2]);
      if (v.w != 0.f) atomicAdd(&cnt[w][(b >> 24) & 0xFFu], v.w * we[c * 4 + 3]);
    }
  }
  const float4* rowI = (const float4*)(Si + (size_t)t * N_I);   // 125 float4
#pragma unroll
  for (int k = 0; k < 2; ++k) {
    int c = k * 64 + lane;
    if (c < 125) {
      float4 v = rowI[c];
      unsigned int b = ii[c];
      if (v.x != 0.f) atomicAdd(&cnt[w][16 + ((b      ) & 0xFFu)], v.x * wi[c * 4 + 0]);
      if (v.y != 0.f) atomicAdd(&cnt[w][16 + ((b >>  8) & 0xFFu)], v.y * wi[c * 4 + 1]);
      if (v.z != 0.f) atomicAdd(&cnt[w][16 + ((b >> 16) & 0xFFu)], v.z * wi[c * 4 + 2]);
      if (v.w != 0.f) atomicAdd(&cnt[w][16 + ((b >> 24) & 0xFFu)], v.w * wi[c * 4 + 3]);
    }
  }
  __syncthreads();
  if (lane < 16) {
    ws[SYNE_OFF + (size_t)t * 16 + lane] = cnt[w][lane];
    ws[SYNI_OFF + (size_t)t * 16 + lane] = cnt[w][16 + lane];
  }
}

// ---------------- conv + tree: transposed LDS tiles, conflict-free ----------------
__global__ __launch_bounds__(256) void conv_tree_kernel(float* __restrict__ ws,
                                                        float* __restrict__ outNs) {
  __shared__ float sE[16][272], sI[16][272];   // transposed, padded rows
  __shared__ float ekL[200 * 16], ikL[200 * 16];
  __shared__ float synR[64][16];
  const int tid = threadIdx.x;
  const int t0 = blockIdx.x * 64;

  for (int p = tid; p < 200 * 16; p += 256) { ekL[p] = ws[EKT_OFF + p]; ikL[p] = ws[IKT_OFF + p]; }
  for (int p = tid; p < 264 * 16; p += 256) {
    int o = p >> 4, s = p & 15;
    int g = t0 - 200 + o;
    bool ok = (g >= 0) && (g < T_DATA);
    sE[s][o] = ok ? ws[SYNE_OFF + (size_t)g * 16 + s] : 0.f;
    sI[s][o] = ok ? ws[SYNI_OFF + (size_t)g * 16 + s] : 0.f;
  }
  __syncthreads();
  {
    const int q = tid >> 6, i = tid & 63;
    const int s0 = q * 4;
    float ax = 0.f, ay = 0.f, az = 0.f, aw = 0.f;
    for (int j = 0; j < T_NO; ++j) {
      int o = i + 200 - j;
      float4 e = *(const float4*)&ekL[j * 16 + s0];   // wave-uniform: broadcast
      float4 k = *(const float4*)&ikL[j * 16 + s0];
      ax = fmaf(e.x, sE[s0 + 0][o], fmaf(k.x, sI[s0 + 0][o], ax));
      ay = fmaf(e.y, sE[s0 + 1][o], fmaf(k.y, sI[s0 + 1][o], ay));
      az = fmaf(e.z, sE[s0 + 2][o], fmaf(k.z, sI[s0 + 2][o], az));
      aw = fmaf(e.w, sE[s0 + 3][o], fmaf(k.w, sI[s0 + 3][o], aw));
    }
    synR[i][s0 + 0] = ax;
    synR[i][s0 + 1] = ay;
    synR[i][s0 + 2] = az;
    synR[i][s0 + 3] = aw;
  }
  __syncthreads();
  if (tid < 64) {
    int t = t0 + tid;
    if (t < T_DATA) {
      const float* prm = ws + PRM_OFF;
      float sv[16];
#pragma unroll
      for (int s = 0; s < 16; ++s) sv[s] = synR[tid][s];
      float ns[SUB];
#pragma unroll
      for (int j = SUB - 1; j >= 1; --j) {
        float x = sv[j] + prm[16 + j];
        if (2 * j + 1 < SUB) x = fmaf(prm[2 * j + 1], ns[2 * j + 1], x);
        if (2 * j + 2 < SUB) x = fmaf(prm[2 * j + 2], ns[2 * j + 2], x);
        ns[j] = softplus_f(x);
      }
      float b = sv[0] + prm[16];
      b = fmaf(prm[1], ns[1], b);
      b = fmaf(prm[2], ns[2], b);
      ws[BT_OFF + t] = b;
      outNs[(size_t)t * SUB] = 0.f;
#pragma unroll
      for (int s = 1; s < SUB; ++s) outNs[(size_t)t * SUB + s] = ns[s];
    }
  }
}

// ---------------- serial scan: pair-parallel ring-FIR, log2 domain ----------------
// hist[0]==0 -> y_t independent of y_{t-1}: steps 2k,2k+1 computed in parallel.
// Fixed register a_r always uses coeff table row r (rotation cancels);
// only the re-seeded register varies per sub-chunk (macro param).
// rt4[u*4+r] = ht[(64r-1-u)&255]; one ds_read_b128 gives all 4 roles.
__global__ __launch_bounds__(64) void scan_kernel(const float* __restrict__ ws,
                                                  float* __restrict__ outV) {
  __shared__ float rt4[320 * 4];
  const int lane = threadIdx.x;
  const float* ht = ws + HT_OFF;
  const float* prm = ws + PRM_OFF;
  const float* bT = ws + BT_OFF;
  for (int p = lane; p < 320 * 4; p += 64) {
    int u = p >> 2, r = p & 3;
    rt4[p] = ht[(64 * r - 1 - u) & 255];
  }
  __syncthreads();
  const float L2E = 1.44269504088896f;
  const float scale2 = 0.6931471805599453f * prm[33];  // ln2 * wsub2[0]
  const float vo = prm[34];
  float a0 = L2E * bT[lane];          // fires in sub-chunks c==0
  float a1 = L2E * bT[64 + lane];     // c==1
  float a2 = L2E * bT[128 + lane];    // c==2
  float a3 = L2E * bT[192 + lane];    // c==3
  float cap = 0.f;
  int ub = (0 - lane) & 255;
  int t0 = 0;
  const bool oddlane = (lane & 1);

#define SUBCHUNK(AC)                                                        \
  {                                                                         \
    const float bnext = L2E * bT[t0 + 256 + lane];                          \
    _Pragma("unroll")                                                       \
    for (int k = 0; k < 32; ++k) {                                          \
      float OB0 = rlane(AC, 2 * k);                                         \
      float OB1 = rlane(AC, 2 * k + 1);                                     \
      float y0 = fast_log2(1.0f + fast_exp2(OB0));                          \
      float y1 = fast_log2(1.0f + fast_exp2(OB1));                          \
      bool pairown = ((lane >> 1) == k);                                    \
      float ysel = oddlane ? y1 : y0;                                       \
      cap = pairown ? ysel : cap;                                           \
      AC = pairown ? bnext : AC;                                            \
      float4 c0 = *(const float4*)&rt4[(ub + 2 * k) * 4];                   \
      float4 c1 = *(const float4*)&rt4[(ub + 2 * k + 1) * 4];               \
      a0 = fmaf(c0.x, y0, a0); a0 = fmaf(c1.x, y1, a0);                     \
      a1 = fmaf(c0.y, y0, a1); a1 = fmaf(c1.y, y1, a1);                     \
      a2 = fmaf(c0.z, y0, a2); a2 = fmaf(c1.z, y1, a2);                     \
      a3 = fmaf(c0.w, y0, a3); a3 = fmaf(c1.w, y1, a3);                     \
    }                                                                       \
    int t = t0 + lane;                                                      \
    if (t < T_DATA) outV[t] = fmaf(cap, scale2, vo);                        \
    ub = (ub + 64) & 255;                                                   \
    t0 += 64;                                                               \
  }

  for (int g = 0; g < 78; ++g) {   // 312 chunks
    SUBCHUNK(a0)
    SUBCHUNK(a1)
    SUBCHUNK(a2)
    SUBCHUNK(a3)
  }
  SUBCHUNK(a0)                     // chunk 312 (t0 = 19968)
#undef SUBCHUNK
}

// ---------------- sentinel ----------------
__global__ __launch_bounds__(256) void sentinel_kernel(float* __restrict__ outV, int code) {
  const int tid = threadIdx.x;
  for (int t = tid; t < T_DATA; t += 256) outV[t] = (float)code;
}

extern "C" void kernel_launch(void* const* d_in, const int* in_sizes, int n_in,
                              void* d_out, int out_size, void* d_ws, size_t ws_size,
                              hipStream_t stream) {
  const float* Se    = (const float*)d_in[0];
  const float* Si    = (const float*)d_in[1];
  const float* Cse   = (const float*)d_in[3];
  const float* Csi   = (const float*)d_in[4];
  const float* cosb  = (const float*)d_in[5];
  const float* Wsyn  = (const float*)d_in[6];
  const float* Wsub  = (const float*)d_in[7];
  const float* Vo    = (const float*)d_in[8];
  const float* Theta = (const float*)d_in[9];
  const float* Whist = (const float*)d_in[10];
  float* ws = (float*)d_ws;
  float* out = (float*)d_out;
  float* outV  = out;                          // final_V: 20000 f32
  float* outNs = out + T_DATA;                 // ns_out: 300000 f32
  float* outF  = out + T_DATA + T_DATA * SUB;  // out_filters: 6200 f32

  int force = 0;
  if (ws_size < (size_t)WS_END * 4 + 1024) force = 3000;
  else if (out_size != 326200) force = 3500;
  if (force) {
    sentinel_kernel<<<1, 256, 0, stream>>>(outV, force);
    return;
  }

  prep_kernel<<<1, 256, 0, stream>>>(Cse, Csi, cosb, Wsyn, Wsub, Vo, Theta, Whist, ws, outF);
  pool_kernel<<<5000, 256, 0, stream>>>(Se, Si, ws);
  conv_tree_kernel<<<313, 256, 0, stream>>>(ws, outNs);
  scan_kernel<<<1, 64, 0, stream>>>(ws, outV);
}

// Round 14
// 903.031 us; speedup vs baseline: 3.3677x; 3.3677x over previous
//
#include <hip/hip_runtime.h>
#include <hip/hip_bf16.h>

// Cos_RootHist_GLM — f32 in/out (passing since round 10, absmax 0.125).
// R14: R13's pair-parallel scan with BOUNDED unroll (8 pairs) — R13's full
// 64x unroll kept 64 float4 coeff loads live -> VGPR 256 + scratch spills
// (WRITE_SIZE 171KB, 367cy/step). Bounded unroll: ~16 loads in flight,
// no spill, chain ~20cy/step.

#define DEVINL __device__ __forceinline__

static constexpr int T_DATA = 20000;
static constexpr int N_E = 2000;
static constexpr int N_I = 500;
static constexpr int SUB = 15;
static constexpr int T_NO = 200;
static constexpr int NB = 19;

// ws layout (f32 offsets) — total 670720 f32 = 2.683 MB
static constexpr int EKT_OFF = 0;       // [200][16] e-kern transposed
static constexpr int IKT_OFF = 3200;    // [200][16]
static constexpr int HT_OFF  = 6400;    // 256
static constexpr int PRM_OFF = 6656;    // 0..14 wsub2, 16..30 theta, 33 scale, 34 vo
static constexpr int WE_OFF  = 6720;    // 2000
static constexpr int WI_OFF  = 8720;    // 500
static constexpr int IDXE_B  = 36880;   // byte off, 2000 uchar
static constexpr int IDXI_B  = 38880;   // byte off, 500 uchar
static constexpr int BT_OFF  = 9856;    // 20736 (zero-padded past 20000)
static constexpr int SYNE_OFF = 30720;  // [20000][16]
static constexpr int SYNI_OFF = 350720; // [20000][16]
static constexpr int WS_END  = 670720;

DEVINL float fast_exp2(float x) {
#if __has_builtin(__builtin_amdgcn_exp2f)
  return __builtin_amdgcn_exp2f(x);
#else
  return exp2f(x);
#endif
}
DEVINL float fast_log2(float x) {
#if __has_builtin(__builtin_amdgcn_logf)
  return __builtin_amdgcn_logf(x);
#else
  return log2f(x);
#endif
}
DEVINL float rlane(float v, int l) {
  return __builtin_bit_cast(float, __builtin_amdgcn_readlane(__builtin_bit_cast(int, v), l));
}

DEVINL float softplus_f(float x) {
  float z = x * 1.44269504088896f;
  float l = 0.6931471805599453f * fast_log2(1.0f + fast_exp2(z));
  return (x > 16.0f) ? x : l;
}

// ---------------- prep ----------------
__global__ __launch_bounds__(256) void prep_kernel(
    const float* __restrict__ Cse, const float* __restrict__ Csi,
    const float* __restrict__ cosb, const float* __restrict__ Wsyn,
    const float* __restrict__ Wsub, const float* __restrict__ Vo,
    const float* __restrict__ Theta, const float* __restrict__ Whist,
    float* __restrict__ ws, float* __restrict__ outF) {
  const int tid = threadIdx.x;
  float* ekT = ws + EKT_OFF;
  float* ikT = ws + IKT_OFF;
  float* ht  = ws + HT_OFF;
  float* prm = ws + PRM_OFF;
  float* we  = ws + WE_OFF;
  float* wi  = ws + WI_OFF;
  unsigned char* idxe = (unsigned char*)ws + IDXE_B;
  unsigned char* idxi = (unsigned char*)ws + IDXI_B;
  float* bT  = ws + BT_OFF;

  for (int p = tid; p < SUB * T_NO; p += 256) {
    int s = p / T_NO, j = p - s * T_NO;
    float ae = 0.f, ai = 0.f;
    for (int b = 0; b < NB; ++b) {
      float cb = cosb[b * T_NO + j];
      ae = fmaf(Wsyn[(s * NB + b) * 2 + 0], cb, ae);
      ai = fmaf(Wsyn[(s * NB + b) * 2 + 1], cb, ai);
    }
    ekT[j * 16 + s] = ae;
    ikT[j * 16 + s] = ai;
    outF[p] = ae;
    outF[SUB * T_NO + p] = ai;
  }
  for (int j = tid; j < T_NO; j += 256) { ekT[j * 16 + 15] = 0.f; ikT[j * 16 + 15] = 0.f; }
  if (tid < 256) {
    float hv = 0.f;
    if (tid < T_NO) {
      for (int b = 0; b < NB; ++b) hv = fmaf(Whist[b], cosb[b * T_NO + tid], hv);
      outF[30 * T_NO + tid] = hv;
    }
    ht[tid] = (tid < T_NO) ? hv : 0.f;   // ht[0] == hist[0] == 0 exactly
  }
  for (int n = tid; n < N_E; n += 256) {
    int id = 0; float w = 0.f;
    for (int s = 0; s < SUB; ++s) { float c = Cse[s * N_E + n]; if (c != 0.f) { id = s; w = c; } }
    idxe[n] = (unsigned char)id; we[n] = w;
  }
  for (int n = tid; n < N_I; n += 256) {
    int id = 0; float w = 0.f;
    for (int s = 0; s < SUB; ++s) { float c = Csi[s * N_I + n]; if (c != 0.f) { id = s; w = c; } }
    idxi[n] = (unsigned char)id; wi[n] = w;
  }
  if (tid < SUB) {
    float w = Wsub[tid];
    prm[tid] = w * w;
    prm[16 + tid] = Theta[tid];
  }
  if (tid == 0) {
    float w0 = Wsub[0];
    prm[33] = w0 * w0;
    prm[34] = Vo[0];
  }
  for (int p = T_DATA + tid; p < T_DATA + 736; p += 256) bT[p] = 0.f;
}

// ---------------- pool: wave per t-row, float4 loads, LDS atomics ----------------
__global__ __launch_bounds__(256) void pool_kernel(
    const float* __restrict__ Se, const float* __restrict__ Si,
    float* __restrict__ ws) {
  __shared__ float cnt[4][32];   // [wave][0:16 E | 16:32 I]
  const int lane = threadIdx.x & 63;
  const int w = threadIdx.x >> 6;
  const int t = blockIdx.x * 4 + w;
  if (lane < 32) cnt[w][lane] = 0.f;
  __syncthreads();
  const float* we = ws + WE_OFF;
  const float* wi = ws + WI_OFF;
  const unsigned int* ie = (const unsigned int*)((const char*)ws + IDXE_B);
  const unsigned int* ii = (const unsigned int*)((const char*)ws + IDXI_B);

  const float4* rowE = (const float4*)(Se + (size_t)t * N_E);   // 500 float4
#pragma unroll
  for (int k = 0; k < 8; ++k) {
    int c = k * 64 + lane;
    if (c < 500) {
      float4 v = rowE[c];
      unsigned int b = ie[c];
      if (v.x != 0.f) atomicAdd(&cnt[w][(b      ) & 0xFFu], v.x * we[c * 4 + 0]);
      if (v.y != 0.f) atomicAdd(&cnt[w][(b >>  8) & 0xFFu], v.y * we[c * 4 + 1]);
      if (v.z != 0.f) atomicAdd(&cnt[w][(b >> 16) & 0xFFu], v.z * we[c * 4 + 2]);
      if (v.w != 0.f) atomicAdd(&cnt[w][(b >> 24) & 0xFFu], v.w * we[c * 4 + 3]);
    }
  }
  const float4* rowI = (const float4*)(Si + (size_t)t * N_I);   // 125 float4
#pragma unroll
  for (int k = 0; k < 2; ++k) {
    int c = k * 64 + lane;
    if (c < 125) {
      float4 v = rowI[c];
      unsigned int b = ii[c];
      if (v.x != 0.f) atomicAdd(&cnt[w][16 + ((b      ) & 0xFFu)], v.x * wi[c * 4 + 0]);
      if (v.y != 0.f) atomicAdd(&cnt[w][16 + ((b >>  8) & 0xFFu)], v.y * wi[c * 4 + 1]);
      if (v.z != 0.f) atomicAdd(&cnt[w][16 + ((b >> 16) & 0xFFu)], v.z * wi[c * 4 + 2]);
      if (v.w != 0.f) atomicAdd(&cnt[w][16 + ((b >> 24) & 0xFFu)], v.w * wi[c * 4 + 3]);
    }
  }
  __syncthreads();
  if (lane < 16) {
    ws[SYNE_OFF + (size_t)t * 16 + lane] = cnt[w][lane];
    ws[SYNI_OFF + (size_t)t * 16 + lane] = cnt[w][16 + lane];
  }
}

// ---------------- conv + tree: transposed LDS tiles, conflict-free ----------------
__global__ __launch_bounds__(256) void conv_tree_kernel(float* __restrict__ ws,
                                                        float* __restrict__ outNs) {
  __shared__ float sE[16][272], sI[16][272];   // transposed, padded rows
  __shared__ float ekL[200 * 16], ikL[200 * 16];
  __shared__ float synR[64][16];
  const int tid = threadIdx.x;
  const int t0 = blockIdx.x * 64;

  for (int p = tid; p < 200 * 16; p += 256) { ekL[p] = ws[EKT_OFF + p]; ikL[p] = ws[IKT_OFF + p]; }
  for (int p = tid; p < 264 * 16; p += 256) {
    int o = p >> 4, s = p & 15;
    int g = t0 - 200 + o;
    bool ok = (g >= 0) && (g < T_DATA);
    sE[s][o] = ok ? ws[SYNE_OFF + (size_t)g * 16 + s] : 0.f;
    sI[s][o] = ok ? ws[SYNI_OFF + (size_t)g * 16 + s] : 0.f;
  }
  __syncthreads();
  {
    const int q = tid >> 6, i = tid & 63;
    const int s0 = q * 4;
    float ax = 0.f, ay = 0.f, az = 0.f, aw = 0.f;
    for (int j = 0; j < T_NO; ++j) {
      int o = i + 200 - j;
      float4 e = *(const float4*)&ekL[j * 16 + s0];   // wave-uniform: broadcast
      float4 k = *(const float4*)&ikL[j * 16 + s0];
      ax = fmaf(e.x, sE[s0 + 0][o], fmaf(k.x, sI[s0 + 0][o], ax));
      ay = fmaf(e.y, sE[s0 + 1][o], fmaf(k.y, sI[s0 + 1][o], ay));
      az = fmaf(e.z, sE[s0 + 2][o], fmaf(k.z, sI[s0 + 2][o], az));
      aw = fmaf(e.w, sE[s0 + 3][o], fmaf(k.w, sI[s0 + 3][o], aw));
    }
    synR[i][s0 + 0] = ax;
    synR[i][s0 + 1] = ay;
    synR[i][s0 + 2] = az;
    synR[i][s0 + 3] = aw;
  }
  __syncthreads();
  if (tid < 64) {
    int t = t0 + tid;
    if (t < T_DATA) {
      const float* prm = ws + PRM_OFF;
      float sv[16];
#pragma unroll
      for (int s = 0; s < 16; ++s) sv[s] = synR[tid][s];
      float ns[SUB];
#pragma unroll
      for (int j = SUB - 1; j >= 1; --j) {
        float x = sv[j] + prm[16 + j];
        if (2 * j + 1 < SUB) x = fmaf(prm[2 * j + 1], ns[2 * j + 1], x);
        if (2 * j + 2 < SUB) x = fmaf(prm[2 * j + 2], ns[2 * j + 2], x);
        ns[j] = softplus_f(x);
      }
      float b = sv[0] + prm[16];
      b = fmaf(prm[1], ns[1], b);
      b = fmaf(prm[2], ns[2], b);
      ws[BT_OFF + t] = b;
      outNs[(size_t)t * SUB] = 0.f;
#pragma unroll
      for (int s = 1; s < SUB; ++s) outNs[(size_t)t * SUB + s] = ns[s];
    }
  }
}

// ---------------- serial scan: pair-parallel ring-FIR, bounded unroll ----------------
// hist[0]==0 -> y_t independent of y_{t-1}: steps 2k,2k+1 in parallel.
// rt4[u*4+r] = ht[(64r-1-u)&255]; one ds_read_b128 per step gives all 4 roles.
// unroll 8: <=16 b128 loads live (no spill), 8-pair lookahead hides LDS latency.
__global__ __launch_bounds__(64) void scan_kernel(const float* __restrict__ ws,
                                                  float* __restrict__ outV) {
  __shared__ float rt4[320 * 4];
  const int lane = threadIdx.x;
  const float* ht = ws + HT_OFF;
  const float* prm = ws + PRM_OFF;
  const float* bT = ws + BT_OFF;
  for (int p = lane; p < 320 * 4; p += 64) {
    int u = p >> 2, r = p & 3;
    rt4[p] = ht[(64 * r - 1 - u) & 255];
  }
  __syncthreads();
  const float L2E = 1.44269504088896f;
  const float scale2 = 0.6931471805599453f * prm[33];  // ln2 * wsub2[0]
  const float vo = prm[34];
  float a0 = L2E * bT[lane];          // fires in sub-chunks c==0
  float a1 = L2E * bT[64 + lane];     // c==1
  float a2 = L2E * bT[128 + lane];    // c==2
  float a3 = L2E * bT[192 + lane];    // c==3
  float cap = 0.f;
  int ub = (0 - lane) & 255;
  int t0 = 0;
  const bool oddlane = (lane & 1);

#define SUBCHUNK(AC)                                                        \
  {                                                                         \
    const float bnext = L2E * bT[t0 + 256 + lane];                          \
    _Pragma("unroll 8")                                                     \
    for (int k = 0; k < 32; ++k) {                                          \
      float OB0 = rlane(AC, 2 * k);                                         \
      float OB1 = rlane(AC, 2 * k + 1);                                     \
      float y0 = fast_log2(1.0f + fast_exp2(OB0));                          \
      float y1 = fast_log2(1.0f + fast_exp2(OB1));                          \
      bool pairown = ((lane >> 1) == k);                                    \
      float ysel = oddlane ? y1 : y0;                                       \
      cap = pairown ? ysel : cap;                                           \
      AC = pairown ? bnext : AC;                                            \
      float4 c0 = *(const float4*)&rt4[(ub + 2 * k) * 4];                   \
      float4 c1 = *(const float4*)&rt4[(ub + 2 * k + 1) * 4];               \
      a0 = fmaf(c0.x, y0, a0); a0 = fmaf(c1.x, y1, a0);                     \
      a1 = fmaf(c0.y, y0, a1); a1 = fmaf(c1.y, y1, a1);                     \
      a2 = fmaf(c0.z, y0, a2); a2 = fmaf(c1.z, y1, a2);                     \
      a3 = fmaf(c0.w, y0, a3); a3 = fmaf(c1.w, y1, a3);                     \
    }                                                                       \
    int t = t0 + lane;                                                      \
    if (t < T_DATA) outV[t] = fmaf(cap, scale2, vo);                        \
    ub = (ub + 64) & 255;                                                   \
    t0 += 64;                                                               \
  }

  for (int g = 0; g < 78; ++g) {   // 312 chunks
    SUBCHUNK(a0)
    SUBCHUNK(a1)
    SUBCHUNK(a2)
    SUBCHUNK(a3)
  }
  SUBCHUNK(a0)                     // chunk 312 (t0 = 19968)
#undef SUBCHUNK
}

// ---------------- sentinel ----------------
__global__ __launch_bounds__(256) void sentinel_kernel(float* __restrict__ outV, int code) {
  const int tid = threadIdx.x;
  for (int t = tid; t < T_DATA; t += 256) outV[t] = (float)code;
}

extern "C" void kernel_launch(void* const* d_in, const int* in_sizes, int n_in,
                              void* d_out, int out_size, void* d_ws, size_t ws_size,
                              hipStream_t stream) {
  const float* Se    = (const float*)d_in[0];
  const float* Si    = (const float*)d_in[1];
  const float* Cse   = (const float*)d_in[3];
  const float* Csi   = (const float*)d_in[4];
  const float* cosb  = (const float*)d_in[5];
  const float* Wsyn  = (const float*)d_in[6];
  const float* Wsub  = (const float*)d_in[7];
  const float* Vo    = (const float*)d_in[8];
  const float* Theta = (const float*)d_in[9];
  const float* Whist = (const float*)d_in[10];
  float* ws = (float*)d_ws;
  float* out = (float*)d_out;
  float* outV  = out;                          // final_V: 20000 f32
  float* outNs = out + T_DATA;                 // ns_out: 300000 f32
  float* outF  = out + T_DATA + T_DATA * SUB;  // out_filters: 6200 f32

  int force = 0;
  if (ws_size < (size_t)WS_END * 4 + 1024) force = 3000;
  else if (out_size != 326200) force = 3500;
  if (force) {
    sentinel_kernel<<<1, 256, 0, stream>>>(outV, force);
    return;
  }

  prep_kernel<<<1, 256, 0, stream>>>(Cse, Csi, cosb, Wsyn, Wsub, Vo, Theta, Whist, ws, outF);
  pool_kernel<<<5000, 256, 0, stream>>>(Se, Si, ws);
  conv_tree_kernel<<<313, 256, 0, stream>>>(ws, outNs);
  scan_kernel<<<1, 64, 0, stream>>>(ws, outV);
}

// Round 15
// 797.977 us; speedup vs baseline: 3.8110x; 1.1317x over previous
//
#include <hip/hip_runtime.h>
#include <hip/hip_bf16.h>

// Cos_RootHist_GLM — f32 in/out (passing since round 10, absmax 0.125).
// R15: scan with HAND-BUILT 4-slot coefficient software pipeline.
//   R13: full unroll -> 256 VGPR + scratch spill (3057us).
//   R14: pragma unroll ignored -> no lookahead, LDS latency exposed (831us).
//   Now: named slot vars + prefetch k+4 inside PAIR + `#pragma unroll 1`
//   on the k4 loop (dynamic backedge = compiler can't hoist or spill).

#define DEVINL __device__ __forceinline__

static constexpr int T_DATA = 20000;
static constexpr int N_E = 2000;
static constexpr int N_I = 500;
static constexpr int SUB = 15;
static constexpr int T_NO = 200;
static constexpr int NB = 19;

// ws layout (f32 offsets) — total 670720 f32 = 2.683 MB
static constexpr int EKT_OFF = 0;       // [200][16] e-kern transposed
static constexpr int IKT_OFF = 3200;    // [200][16]
static constexpr int HT_OFF  = 6400;    // 256
static constexpr int PRM_OFF = 6656;    // 0..14 wsub2, 16..30 theta, 33 scale, 34 vo
static constexpr int WE_OFF  = 6720;    // 2000
static constexpr int WI_OFF  = 8720;    // 500
static constexpr int IDXE_B  = 36880;   // byte off, 2000 uchar
static constexpr int IDXI_B  = 38880;   // byte off, 500 uchar
static constexpr int BT_OFF  = 9856;    // 20736 (zero-padded past 20000)
static constexpr int SYNE_OFF = 30720;  // [20000][16]
static constexpr int SYNI_OFF = 350720; // [20000][16]
static constexpr int WS_END  = 670720;

DEVINL float fast_exp2(float x) {
#if __has_builtin(__builtin_amdgcn_exp2f)
  return __builtin_amdgcn_exp2f(x);
#else
  return exp2f(x);
#endif
}
DEVINL float fast_log2(float x) {
#if __has_builtin(__builtin_amdgcn_logf)
  return __builtin_amdgcn_logf(x);
#else
  return log2f(x);
#endif
}
DEVINL float rlane(float v, int l) {
  return __builtin_bit_cast(float, __builtin_amdgcn_readlane(__builtin_bit_cast(int, v), l));
}

DEVINL float softplus_f(float x) {
  float z = x * 1.44269504088896f;
  float l = 0.6931471805599453f * fast_log2(1.0f + fast_exp2(z));
  return (x > 16.0f) ? x : l;
}

// ---------------- prep ----------------
__global__ __launch_bounds__(256) void prep_kernel(
    const float* __restrict__ Cse, const float* __restrict__ Csi,
    const float* __restrict__ cosb, const float* __restrict__ Wsyn,
    const float* __restrict__ Wsub, const float* __restrict__ Vo,
    const float* __restrict__ Theta, const float* __restrict__ Whist,
    float* __restrict__ ws, float* __restrict__ outF) {
  const int tid = threadIdx.x;
  float* ekT = ws + EKT_OFF;
  float* ikT = ws + IKT_OFF;
  float* ht  = ws + HT_OFF;
  float* prm = ws + PRM_OFF;
  float* we  = ws + WE_OFF;
  float* wi  = ws + WI_OFF;
  unsigned char* idxe = (unsigned char*)ws + IDXE_B;
  unsigned char* idxi = (unsigned char*)ws + IDXI_B;
  float* bT  = ws + BT_OFF;

  for (int p = tid; p < SUB * T_NO; p += 256) {
    int s = p / T_NO, j = p - s * T_NO;
    float ae = 0.f, ai = 0.f;
    for (int b = 0; b < NB; ++b) {
      float cb = cosb[b * T_NO + j];
      ae = fmaf(Wsyn[(s * NB + b) * 2 + 0], cb, ae);
      ai = fmaf(Wsyn[(s * NB + b) * 2 + 1], cb, ai);
    }
    ekT[j * 16 + s] = ae;
    ikT[j * 16 + s] = ai;
    outF[p] = ae;
    outF[SUB * T_NO + p] = ai;
  }
  for (int j = tid; j < T_NO; j += 256) { ekT[j * 16 + 15] = 0.f; ikT[j * 16 + 15] = 0.f; }
  if (tid < 256) {
    float hv = 0.f;
    if (tid < T_NO) {
      for (int b = 0; b < NB; ++b) hv = fmaf(Whist[b], cosb[b * T_NO + tid], hv);
      outF[30 * T_NO + tid] = hv;
    }
    ht[tid] = (tid < T_NO) ? hv : 0.f;   // ht[0] == hist[0] == 0 exactly
  }
  for (int n = tid; n < N_E; n += 256) {
    int id = 0; float w = 0.f;
    for (int s = 0; s < SUB; ++s) { float c = Cse[s * N_E + n]; if (c != 0.f) { id = s; w = c; } }
    idxe[n] = (unsigned char)id; we[n] = w;
  }
  for (int n = tid; n < N_I; n += 256) {
    int id = 0; float w = 0.f;
    for (int s = 0; s < SUB; ++s) { float c = Csi[s * N_I + n]; if (c != 0.f) { id = s; w = c; } }
    idxi[n] = (unsigned char)id; wi[n] = w;
  }
  if (tid < SUB) {
    float w = Wsub[tid];
    prm[tid] = w * w;
    prm[16 + tid] = Theta[tid];
  }
  if (tid == 0) {
    float w0 = Wsub[0];
    prm[33] = w0 * w0;
    prm[34] = Vo[0];
  }
  for (int p = T_DATA + tid; p < T_DATA + 736; p += 256) bT[p] = 0.f;
}

// ---------------- pool: wave per t-row, float4 loads, LDS atomics ----------------
__global__ __launch_bounds__(256) void pool_kernel(
    const float* __restrict__ Se, const float* __restrict__ Si,
    float* __restrict__ ws) {
  __shared__ float cnt[4][32];   // [wave][0:16 E | 16:32 I]
  const int lane = threadIdx.x & 63;
  const int w = threadIdx.x >> 6;
  const int t = blockIdx.x * 4 + w;
  if (lane < 32) cnt[w][lane] = 0.f;
  __syncthreads();
  const float* we = ws + WE_OFF;
  const float* wi = ws + WI_OFF;
  const unsigned int* ie = (const unsigned int*)((const char*)ws + IDXE_B);
  const unsigned int* ii = (const unsigned int*)((const char*)ws + IDXI_B);

  const float4* rowE = (const float4*)(Se + (size_t)t * N_E);   // 500 float4
#pragma unroll
  for (int k = 0; k < 8; ++k) {
    int c = k * 64 + lane;
    if (c < 500) {
      float4 v = rowE[c];
      unsigned int b = ie[c];
      if (v.x != 0.f) atomicAdd(&cnt[w][(b      ) & 0xFFu], v.x * we[c * 4 + 0]);
      if (v.y != 0.f) atomicAdd(&cnt[w][(b >>  8) & 0xFFu], v.y * we[c * 4 + 1]);
      if (v.z != 0.f) atomicAdd(&cnt[w][(b >> 16) & 0xFFu], v.z * we[c * 4 + 2]);
      if (v.w != 0.f) atomicAdd(&cnt[w][(b >> 24) & 0xFFu], v.w * we[c * 4 + 3]);
    }
  }
  const float4* rowI = (const float4*)(Si + (size_t)t * N_I);   // 125 float4
#pragma unroll
  for (int k = 0; k < 2; ++k) {
    int c = k * 64 + lane;
    if (c < 125) {
      float4 v = rowI[c];
      unsigned int b = ii[c];
      if (v.x != 0.f) atomicAdd(&cnt[w][16 + ((b      ) & 0xFFu)], v.x * wi[c * 4 + 0]);
      if (v.y != 0.f) atomicAdd(&cnt[w][16 + ((b >>  8) & 0xFFu)], v.y * wi[c * 4 + 1]);
      if (v.z != 0.f) atomicAdd(&cnt[w][16 + ((b >> 16) & 0xFFu)], v.z * wi[c * 4 + 2]);
      if (v.w != 0.f) atomicAdd(&cnt[w][16 + ((b >> 24) & 0xFFu)], v.w * wi[c * 4 + 3]);
    }
  }
  __syncthreads();
  if (lane < 16) {
    ws[SYNE_OFF + (size_t)t * 16 + lane] = cnt[w][lane];
    ws[SYNI_OFF + (size_t)t * 16 + lane] = cnt[w][16 + lane];
  }
}

// ---------------- conv + tree: transposed LDS tiles, conflict-free ----------------
__global__ __launch_bounds__(256) void conv_tree_kernel(float* __restrict__ ws,
                                                        float* __restrict__ outNs) {
  __shared__ float sE[16][272], sI[16][272];   // transposed, padded rows
  __shared__ float ekL[200 * 16], ikL[200 * 16];
  __shared__ float synR[64][16];
  const int tid = threadIdx.x;
  const int t0 = blockIdx.x * 64;

  for (int p = tid; p < 200 * 16; p += 256) { ekL[p] = ws[EKT_OFF + p]; ikL[p] = ws[IKT_OFF + p]; }
  for (int p = tid; p < 264 * 16; p += 256) {
    int o = p >> 4, s = p & 15;
    int g = t0 - 200 + o;
    bool ok = (g >= 0) && (g < T_DATA);
    sE[s][o] = ok ? ws[SYNE_OFF + (size_t)g * 16 + s] : 0.f;
    sI[s][o] = ok ? ws[SYNI_OFF + (size_t)g * 16 + s] : 0.f;
  }
  __syncthreads();
  {
    const int q = tid >> 6, i = tid & 63;
    const int s0 = q * 4;
    float ax = 0.f, ay = 0.f, az = 0.f, aw = 0.f;
    for (int j = 0; j < T_NO; ++j) {
      int o = i + 200 - j;
      float4 e = *(const float4*)&ekL[j * 16 + s0];   // wave-uniform: broadcast
      float4 k = *(const float4*)&ikL[j * 16 + s0];
      ax = fmaf(e.x, sE[s0 + 0][o], fmaf(k.x, sI[s0 + 0][o], ax));
      ay = fmaf(e.y, sE[s0 + 1][o], fmaf(k.y, sI[s0 + 1][o], ay));
      az = fmaf(e.z, sE[s0 + 2][o], fmaf(k.z, sI[s0 + 2][o], az));
      aw = fmaf(e.w, sE[s0 + 3][o], fmaf(k.w, sI[s0 + 3][o], aw));
    }
    synR[i][s0 + 0] = ax;
    synR[i][s0 + 1] = ay;
    synR[i][s0 + 2] = az;
    synR[i][s0 + 3] = aw;
  }
  __syncthreads();
  if (tid < 64) {
    int t = t0 + tid;
    if (t < T_DATA) {
      const float* prm = ws + PRM_OFF;
      float sv[16];
#pragma unroll
      for (int s = 0; s < 16; ++s) sv[s] = synR[tid][s];
      float ns[SUB];
#pragma unroll
      for (int j = SUB - 1; j >= 1; --j) {
        float x = sv[j] + prm[16 + j];
        if (2 * j + 1 < SUB) x = fmaf(prm[2 * j + 1], ns[2 * j + 1], x);
        if (2 * j + 2 < SUB) x = fmaf(prm[2 * j + 2], ns[2 * j + 2], x);
        ns[j] = softplus_f(x);
      }
      float b = sv[0] + prm[16];
      b = fmaf(prm[1], ns[1], b);
      b = fmaf(prm[2], ns[2], b);
      ws[BT_OFF + t] = b;
      outNs[(size_t)t * SUB] = 0.f;
#pragma unroll
      for (int s = 1; s < SUB; ++s) outNs[(size_t)t * SUB + s] = ns[s];
    }
  }
}

// ---------------- serial scan: pair-parallel ring-FIR, 4-slot pipeline ----------------
// hist[0]==0 -> steps 2k,2k+1 in parallel. rt4[u*4+r] = ht[(64r-1-u)&255];
// one b128 per step. Slots A-D hold pairs k..k+3; PAIR consumes then
// prefetches k+4 (distance 4 ≈ 160cy ALU > 120cy LDS latency).
// `unroll 1` on the k4 loop: dynamic backedge blocks whole-loop hoist/spill.
__global__ __launch_bounds__(64) void scan_kernel(const float* __restrict__ ws,
                                                  float* __restrict__ outV) {
  __shared__ float rt4[336 * 4];
  const int lane = threadIdx.x;
  const float* ht = ws + HT_OFF;
  const float* prm = ws + PRM_OFF;
  const float* bT = ws + BT_OFF;
  for (int p = lane; p < 336 * 4; p += 64) {
    int u = p >> 2, r = p & 3;
    rt4[p] = ht[(64 * r - 1 - u) & 255];
  }
  __syncthreads();
  const float L2E = 1.44269504088896f;
  const float scale2 = 0.6931471805599453f * prm[33];  // ln2 * wsub2[0]
  const float vo = prm[34];
  float a0 = L2E * bT[lane];          // fires in sub-chunks c==0
  float a1 = L2E * bT[64 + lane];     // c==1
  float a2 = L2E * bT[128 + lane];    // c==2
  float a3 = L2E * bT[192 + lane];    // c==3
  float cap = 0.f;
  const int myk = lane >> 1;
  const bool oddlane = (lane & 1);
  int ub = (0 - lane) & 255;
  int t0 = 0;
  const float* rp = &rt4[0];

#define PAIR(AC, K, C0, C1)                                                 \
  {                                                                         \
    float OB0 = rlane(AC, 2 * (K));                                         \
    float OB1 = rlane(AC, 2 * (K) + 1);                                     \
    float y0 = fast_log2(1.0f + fast_exp2(OB0));                            \
    float y1 = fast_log2(1.0f + fast_exp2(OB1));                            \
    bool own = (myk == (K));                                                \
    cap = own ? (oddlane ? y1 : y0) : cap;                                  \
    AC = own ? bnext : AC;                                                  \
    a0 = fmaf(C0.x, y0, a0); a0 = fmaf(C1.x, y1, a0);                       \
    a1 = fmaf(C0.y, y0, a1); a1 = fmaf(C1.y, y1, a1);                       \
    a2 = fmaf(C0.z, y0, a2); a2 = fmaf(C1.z, y1, a2);                       \
    a3 = fmaf(C0.w, y0, a3); a3 = fmaf(C1.w, y1, a3);                       \
    C0 = *(const float4*)(rp + (2 * (K) + 8) * 4);                          \
    C1 = *(const float4*)(rp + (2 * (K) + 9) * 4);                          \
  }

#define SUBCHUNK(AC)                                                        \
  {                                                                         \
    const float bnext = L2E * bT[t0 + 256 + lane];                          \
    rp = &rt4[ub * 4];                                                      \
    float4 cA0 = *(const float4*)(rp + 0);                                  \
    float4 cA1 = *(const float4*)(rp + 4);                                  \
    float4 cB0 = *(const float4*)(rp + 8);                                  \
    float4 cB1 = *(const float4*)(rp + 12);                                 \
    float4 cC0 = *(const float4*)(rp + 16);                                 \
    float4 cC1 = *(const float4*)(rp + 20);                                 \
    float4 cD0 = *(const float4*)(rp + 24);                                 \
    float4 cD1 = *(const float4*)(rp + 28);                                 \
    _Pragma("unroll 1")                                                     \
    for (int k4 = 0; k4 < 8; ++k4) {                                        \
      PAIR(AC, 4 * k4 + 0, cA0, cA1)                                        \
      PAIR(AC, 4 * k4 + 1, cB0, cB1)                                        \
      PAIR(AC, 4 * k4 + 2, cC0, cC1)                                        \
      PAIR(AC, 4 * k4 + 3, cD0, cD1)                                        \
    }                                                                       \
    int t = t0 + lane;                                                      \
    if (t < T_DATA) outV[t] = fmaf(cap, scale2, vo);                        \
    ub = (ub + 64) & 255;                                                   \
    t0 += 64;                                                               \
  }

  for (int g = 0; g < 78; ++g) {   // 312 chunks
    SUBCHUNK(a0)
    SUBCHUNK(a1)
    SUBCHUNK(a2)
    SUBCHUNK(a3)
  }
  SUBCHUNK(a0)                     // chunk 312 (t0 = 19968)
#undef PAIR
#undef SUBCHUNK
}

// ---------------- sentinel ----------------
__global__ __launch_bounds__(256) void sentinel_kernel(float* __restrict__ outV, int code) {
  const int tid = threadIdx.x;
  for (int t = tid; t < T_DATA; t += 256) outV[t] = (float)code;
}

extern "C" void kernel_launch(void* const* d_in, const int* in_sizes, int n_in,
                              void* d_out, int out_size, void* d_ws, size_t ws_size,
                              hipStream_t stream) {
  const float* Se    = (const float*)d_in[0];
  const float* Si    = (const float*)d_in[1];
  const float* Cse   = (const float*)d_in[3];
  const float* Csi   = (const float*)d_in[4];
  const float* cosb  = (const float*)d_in[5];
  const float* Wsyn  = (const float*)d_in[6];
  const float* Wsub  = (const float*)d_in[7];
  const float* Vo    = (const float*)d_in[8];
  const float* Theta = (const float*)d_in[9];
  const float* Whist = (const float*)d_in[10];
  float* ws = (float*)d_ws;
  float* out = (float*)d_out;
  float* outV  = out;                          // final_V: 20000 f32
  float* outNs = out + T_DATA;                 // ns_out: 300000 f32
  float* outF  = out + T_DATA + T_DATA * SUB;  // out_filters: 6200 f32

  int force = 0;
  if (ws_size < (size_t)WS_END * 4 + 1024) force = 3000;
  else if (out_size != 326200) force = 3500;
  if (force) {
    sentinel_kernel<<<1, 256, 0, stream>>>(outV, force);
    return;
  }

  prep_kernel<<<1, 256, 0, stream>>>(Cse, Csi, cosb, Wsyn, Wsub, Vo, Theta, Whist, ws, outF);
  pool_kernel<<<5000, 256, 0, stream>>>(Se, Si, ws);
  conv_tree_kernel<<<313, 256, 0, stream>>>(ws, outNs);
  scan_kernel<<<1, 64, 0, stream>>>(ws, outV);
}